// Round 9
// baseline (528.394 us; speedup 1.0000x reference)
//
#include <hip/hip_runtime.h>
#include <hip/hip_bf16.h>

typedef unsigned short u16;
typedef __attribute__((ext_vector_type(8))) __bf16 bf16x8;
typedef __attribute__((ext_vector_type(4))) float f32x4;

#define AS1 __attribute__((address_space(1)))
#define AS3 __attribute__((address_space(3)))

__device__ inline void gload_lds16(const void* g, void* l) {
  __builtin_amdgcn_global_load_lds((const AS1 void*)g, (AS3 void*)l, 16, 0, 0);
}

__device__ inline u16 f2bf(float f) {
  __bf16 h = (__bf16)f;
  return __builtin_bit_cast(u16, h);
}

// ---------------- fused weight transpose + bf16 convert ----------------
__global__ void conv_weights(const float* __restrict__ W1, const float* __restrict__ W2,
                             const float* __restrict__ W3, u16* __restrict__ w1t,
                             u16* __restrict__ w2t, u16* __restrict__ w3t) {
  int e = blockIdx.x * 256 + threadIdx.x;          // 0 .. 212991
  if (e < 131072) {
    int h = e >> 9, f = e & 511;
    w1t[e] = f2bf(W1[f * 256 + h]);
  } else if (e < 196608) {
    int x = e - 131072;
    int n = x >> 8, k = x & 255;
    w2t[x] = f2bf(W2[k * 256 + n]);
  } else if (e < 212992) {
    int x = e - 196608;
    int n = x >> 8, k = x & 255;
    w3t[x] = f2bf(W3[k * 64 + n]);
  }
}

// ================= fully-fused MLP (unchanged from R8) =================
__global__ __launch_bounds__(256, 2) void mlp_kernel(const float* __restrict__ X,
                                                     const u16* __restrict__ W1t,
                                                     const u16* __restrict__ W2t,
                                                     const u16* __restrict__ W3t,
                                                     float* __restrict__ lg) {
  __shared__ alignas(16) char smem[69632];
  u16* As   = (u16*)smem;                 // [64][32]   4 KB
  u16* Bs   = (u16*)(smem + 4096);        // [256][32] 16 KB
  u16* h1s  = (u16*)(smem + 20480);       // [64][256] 32 KB, elem-idx ^ ((row&7)<<3)
  u16* quad = (u16*)(smem + 53248);       // [64][64]   8 KB, swizzled
  u16* w3s  = (u16*)(smem + 61440);       // [64][64]   8 KB, swizzled
  const int bm = blockIdx.x, t = threadIdx.x;
  const int wid = t >> 6, lane = t & 63;
  const int wr = wid >> 1, wc = wid & 1;
  const int l15 = lane & 15, lk = lane >> 4;
  const f32x4 z = {0.f, 0.f, 0.f, 0.f};

  // ---- phase 1: h1s = relu(X[bm stripe] @ W1) ----
  {
    f32x4 acc[2][8];
#pragma unroll
    for (int i = 0; i < 2; ++i)
#pragma unroll
      for (int j = 0; j < 8; ++j) acc[i][j] = z;

    for (int k0 = 0; k0 < 512; k0 += 32) {
#pragma unroll
      for (int it = 0; it < 4; ++it) {          // W1 tile [256][32]
        int s = it * 256 + t;
        gload_lds16(W1t + (size_t)(s >> 2) * 512 + k0 + (s & 3) * 8,
                    &Bs[(it * 256 + wid * 64) * 8]);
      }
      {                                          // X tile [64][32] fp32->bf16
        const float* src = X + (size_t)(bm * 64 + (t >> 2)) * 512 + k0 + (t & 3) * 8;
        float4 v0 = *(const float4*)src;
        float4 v1 = *(const float4*)(src + 4);
        bf16x8 wv;
        wv[0] = (__bf16)v0.x; wv[1] = (__bf16)v0.y; wv[2] = (__bf16)v0.z; wv[3] = (__bf16)v0.w;
        wv[4] = (__bf16)v1.x; wv[5] = (__bf16)v1.y; wv[6] = (__bf16)v1.z; wv[7] = (__bf16)v1.w;
        *(bf16x8*)&As[t * 8] = wv;
      }
      __syncthreads();
      bf16x8 af[2], bfr[8];
#pragma unroll
      for (int i = 0; i < 2; ++i)
        af[i] = *(const bf16x8*)&As[(wr * 32 + i * 16 + l15) * 32 + lk * 8];
#pragma unroll
      for (int j = 0; j < 8; ++j)
        bfr[j] = *(const bf16x8*)&Bs[(wc * 128 + j * 16 + l15) * 32 + lk * 8];
#pragma unroll
      for (int i = 0; i < 2; ++i)
#pragma unroll
        for (int j = 0; j < 8; ++j)
          acc[i][j] = __builtin_amdgcn_mfma_f32_16x16x32_bf16(af[i], bfr[j], acc[i][j], 0, 0, 0);
      __syncthreads();
    }
#pragma unroll
    for (int i = 0; i < 2; ++i)
#pragma unroll
      for (int j = 0; j < 8; ++j)
#pragma unroll
        for (int r = 0; r < 4; ++r) {
          int row = wr * 32 + i * 16 + lk * 4 + r;
          int col = wc * 128 + j * 16 + l15;
          h1s[(row * 256 + col) ^ ((row & 7) << 3)] = f2bf(fmaxf(acc[i][j][r], 0.f));
        }
    __syncthreads();
  }

  // ---- phase 2: acc2 = h1s @ W2 ----
  f32x4 acc2[2][8];
#pragma unroll
  for (int i = 0; i < 2; ++i)
#pragma unroll
    for (int j = 0; j < 8; ++j) acc2[i][j] = z;

  for (int k0 = 0; k0 < 256; k0 += 32) {
#pragma unroll
    for (int it = 0; it < 4; ++it) {            // W2 tile [256][32]
      int s = it * 256 + t;
      gload_lds16(W2t + (size_t)(s >> 2) * 256 + k0 + (s & 3) * 8,
                  &Bs[(it * 256 + wid * 64) * 8]);
    }
    __syncthreads();
    bf16x8 af[2], bfr[8];
#pragma unroll
    for (int i = 0; i < 2; ++i) {
      int row = wr * 32 + i * 16 + l15;
      af[i] = *(const bf16x8*)&h1s[(row * 256 + k0 + lk * 8) ^ ((row & 7) << 3)];
    }
#pragma unroll
    for (int j = 0; j < 8; ++j)
      bfr[j] = *(const bf16x8*)&Bs[(wc * 128 + j * 16 + l15) * 32 + lk * 8];
#pragma unroll
    for (int i = 0; i < 2; ++i)
#pragma unroll
      for (int j = 0; j < 8; ++j)
        acc2[i][j] = __builtin_amdgcn_mfma_f32_16x16x32_bf16(af[i], bfr[j], acc2[i][j], 0, 0, 0);
    __syncthreads();
  }

  // ---- phase 3: lg = relu(acc2) @ W3 via swizzled LDS bounce ----
  f32x4 acc3[4];
#pragma unroll
  for (int j = 0; j < 4; ++j) acc3[j] = z;

#pragma unroll
  for (int kk = 0; kk < 4; ++kk) {
    if (wc == (kk >> 1)) {
#pragma unroll
      for (int i = 0; i < 2; ++i)
#pragma unroll
        for (int j4 = 0; j4 < 4; ++j4) {
          int j = (kk & 1) * 4 + j4;
#pragma unroll
          for (int r = 0; r < 4; ++r) {
            int row = wr * 32 + i * 16 + lk * 4 + r;
            int c   = j4 * 16 + l15;
            quad[(row * 64 + c) ^ ((row & 7) << 3)] = f2bf(fmaxf(acc2[i][j][r], 0.f));
          }
        }
    }
#pragma unroll
    for (int it = 0; it < 2; ++it) {
      int s = it * 256 + t;
      int col = s >> 3;
      int koff = ((s ^ (col & 7)) & 7) * 8;
      gload_lds16(W3t + (size_t)col * 256 + kk * 64 + koff, &w3s[(it * 256 + wid * 64) * 8]);
    }
    __syncthreads();
    bf16x8 af2, bfr2[4];
#pragma unroll
    for (int ks = 0; ks < 2; ++ks) {
#pragma unroll
      for (int j2 = 0; j2 < 4; ++j2) {
        int col = j2 * 16 + l15;
        bfr2[j2] = *(const bf16x8*)&w3s[(col * 64 + ks * 32 + lk * 8) ^ ((col & 7) << 3)];
      }
      {
        int row = wid * 16 + l15;
        af2 = *(const bf16x8*)&quad[(row * 64 + ks * 32 + lk * 8) ^ ((row & 7) << 3)];
      }
#pragma unroll
      for (int j2 = 0; j2 < 4; ++j2)
        acc3[j2] = __builtin_amdgcn_mfma_f32_16x16x32_bf16(af2, bfr2[j2], acc3[j2], 0, 0, 0);
    }
    __syncthreads();
  }

#pragma unroll
  for (int j2 = 0; j2 < 4; ++j2) {
    int col = j2 * 16 + l15;
#pragma unroll
    for (int r = 0; r < 4; ++r) {
      int row = wid * 16 + lk * 4 + r;
      lg[(size_t)(bm * 64 + row) * 64 + col] = acc3[j2][r];
    }
  }
}

// ================= fused topk + soft-k-medoid per ppr row =================
// REPEAT is a DIAGNOSTIC knob: the scan phase runs REPEAT times with state
// reset per rep (bitwise-identical result, deterministic). REPEAT=2 pushes
// this kernel past the harness's ~318us fill dispatches so it appears in
// rocprof top-5 with its own hbm_gbps/Occupancy/VALUBusy.
// Scan is now a 3-deep software pipeline: 12 float4 loads in flight per wave;
// compiler emits counted vmcnt waits on first use of each batch (T4-style),
// fixing the per-iteration vmcnt(0) drain of the 2-deep version.
template <int REPEAT>
__global__ __launch_bounds__(256, 4) void topk_medoid(const float* __restrict__ ppr,
                                                      const float* __restrict__ lg,
                                                      float* __restrict__ out) {
  __shared__ alignas(16) char smem[13312];
  float* cvals   = (float*)smem;              // [1024] (phase 1-2)
  int*   cidx    = (int*)(smem + 4096);       // [1024] (phase 1-2)
  float* xk      = (float*)smem;              // [32][65] (phase 3, aliases cvals/cidx)
  float* l2m     = (float*)(smem + 8448);     // [32][33]
  float* vals    = (float*)(smem + 12672);    // [32]
  int*   idxs    = (int*)(smem + 12800);      // [32] (also fallback's sel)
  float* dist    = (float*)(smem + 12928);    // [32]
  float* wgt     = (float*)(smem + 13056);    // [32]
  float* partial = (float*)(smem + 13184);    // [4]
  int*   cnt     = (int*)(smem + 13200);      // [1]
  float* rsum    = (float*)(smem + 13204);    // [1]

  const int b = blockIdx.x, t = threadIdx.x;
  const int lane = t & 63, wid = t >> 6;
  const float* row = ppr + (size_t)b * 65536;
  const float4* rp = (const float4*)row;
  const float T0 = 0.997f;

  float sum;
#pragma unroll 1
  for (int rep = 0; rep < REPEAT; ++rep) {
    if (t == 0) *cnt = 0;
    __syncthreads();
    sum = 0.f;

    auto consume = [&](float4 v0, float4 v1, float4 v2, float4 v3, int it) {
      float4 cs[4] = {v0, v1, v2, v3};
#pragma unroll
      for (int q = 0; q < 4; ++q) {
        float4 v = cs[q];
        sum += (v.x + v.y) + (v.z + v.w);
        float mx = fmaxf(fmaxf(v.x, v.y), fmaxf(v.z, v.w));
        if (mx > T0) {
          int fb = (it * 1024 + q * 256 + t) * 4;
          float xs[4] = {v.x, v.y, v.z, v.w};
#pragma unroll
          for (int j = 0; j < 4; ++j) {
            if (xs[j] > T0) {
              int p = atomicAdd(cnt, 1);
              if (p < 1024) { cvals[p] = xs[j]; cidx[p] = fb + j; }
            }
          }
        }
      }
    };

    // 3-deep pipeline over 16 batches of 4 float4
    float4 A0 = rp[t],        A1 = rp[t + 256],  A2 = rp[t + 512],  A3 = rp[t + 768];
    float4 B0 = rp[t + 1024], B1 = rp[t + 1280], B2 = rp[t + 1536], B3 = rp[t + 1792];
    float4 C0, C1, C2, C3;
#pragma unroll
    for (int it = 0; it < 14; ++it) {
      int nb = (it + 2) * 1024 + t;
      C0 = rp[nb]; C1 = rp[nb + 256]; C2 = rp[nb + 512]; C3 = rp[nb + 768];
      consume(A0, A1, A2, A3, it);
      A0 = B0; A1 = B1; A2 = B2; A3 = B3;
      B0 = C0; B1 = C1; B2 = C2; B3 = C3;
    }
    consume(A0, A1, A2, A3, 14);
    consume(B0, B1, B2, B3, 15);
    __syncthreads();   // all inserts visible before (a) next rep reset, (b) extraction
  }

#pragma unroll
  for (int off = 32; off > 0; off >>= 1) sum += __shfl_down(sum, off);
  if (lane == 0) partial[wid] = sum;
  __syncthreads();

  // ---- phase 2: wave0 extraction (val desc, idx asc == jax.lax.top_k) ----
  if (wid == 0) {
    if (lane == 0) *rsum = partial[0] + partial[1] + partial[2] + partial[3];
    const int ncand = *cnt;
    const int n = ncand < 1024 ? ncand : 1024;
    if (n >= 32 && ncand <= 1024) {
      for (int r = 0; r < 32; ++r) {
        float bv = -__builtin_inff();
        int bi = 0x7fffffff, bp = -1;
        for (int p = lane; p < n; p += 64) {
          float xv = cvals[p];
          int xi = cidx[p];
          if (xv > bv || (xv == bv && xi < bi)) { bv = xv; bi = xi; bp = p; }
        }
#pragma unroll
        for (int off = 32; off > 0; off >>= 1) {
          float ov = __shfl_down(bv, off);
          int   oi = __shfl_down(bi, off);
          int   op = __shfl_down(bp, off);
          if (ov > bv || (ov == bv && oi < bi)) { bv = ov; bi = oi; bp = op; }
        }
        if (lane == 0) {
          vals[r] = bv; idxs[r] = bi;
          if (bp >= 0) { cvals[bp] = -__builtin_inff(); cidx[bp] = 0x7fffffff; }
        }
      }
    } else {
      // exact fallback (never taken for uniform data)
      for (int r = 0; r < 32; ++r) {
        float bv = -__builtin_inff();
        int bi = 0x7fffffff;
        for (int p = lane; p < 65536; p += 64) {
          float xv = row[p];
          bool skip = false;
          for (int q = 0; q < r; ++q) skip = skip || (idxs[q] == p);
          if (!skip && (xv > bv || (xv == bv && p < bi))) { bv = xv; bi = p; }
        }
#pragma unroll
        for (int off = 32; off > 0; off >>= 1) {
          float ov = __shfl_down(bv, off);
          int   oi = __shfl_down(bi, off);
          if (ov > bv || (ov == bv && oi < bi)) { bv = ov; bi = oi; }
        }
        if (lane == 0) { vals[r] = bv; idxs[r] = bi; }
      }
    }
  }
  __syncthreads();

  // ---- phase 3: medoid on own result ----
  const float rs_b = *rsum;
#pragma unroll
  for (int j = 0; j < 8; ++j) {
    int s = j * 256 + t;
    int r = s >> 6, c = s & 63;
    xk[r * 65 + c] = lg[(size_t)idxs[r] * 64 + c];
  }
  __syncthreads();
#pragma unroll
  for (int j = 0; j < 4; ++j) {
    int p = j * 256 + t;
    int c = p >> 5, m = p & 31;
    float d = 0.f;
#pragma unroll
    for (int ch = 0; ch < 64; ++ch) {
      float df = xk[c * 65 + ch] - xk[m * 65 + ch];
      d += df * df;
    }
    l2m[c * 33 + m] = sqrtf(d + 1e-12f);
  }
  __syncthreads();
  if (t < 32) {
    float d = 0.f;
#pragma unroll
    for (int m = 0; m < 32; ++m) d += vals[m] * l2m[t * 33 + m];
    if (vals[t] == 0.f) d = 3.402823466e+38f;
    dist[t] = d;
  }
  __syncthreads();
  if (t == 0) {
    float mx = -3.402823466e+38f;
    for (int c = 0; c < 32; ++c) mx = fmaxf(mx, -dist[c]);
    float s = 0.f;
    for (int c = 0; c < 32; ++c) { float e = expf(-dist[c] - mx); wgt[c] = e; s += e; }
    float s2 = 0.f;
    for (int c = 0; c < 32; ++c) { wgt[c] = wgt[c] / s * vals[c]; s2 += wgt[c]; }
    float inv = 1.f / s2;
    for (int c = 0; c < 32; ++c) wgt[c] *= inv;
  }
  __syncthreads();
  if (t < 64) {
    float o = 0.f;
#pragma unroll
    for (int k = 0; k < 32; ++k) o += wgt[k] * xk[k * 65 + t];
    out[(size_t)b * 64 + t] = rs_b * o;
  }
}

// ---------------- launch ----------------
extern "C" void kernel_launch(void* const* d_in, const int* in_sizes, int n_in,
                              void* d_out, int out_size, void* d_ws, size_t ws_size,
                              hipStream_t stream) {
  const float* X   = (const float*)d_in[0];
  const float* ppr = (const float*)d_in[1];
  const float* W1  = (const float*)d_in[2];
  const float* W2  = (const float*)d_in[3];
  const float* W3  = (const float*)d_in[4];
  float* out = (float*)d_out;
  char* ws = (char*)d_ws;

  u16*  w1t = (u16*)(ws + 0);                    // 256x512 bf16
  u16*  w2t = (u16*)(ws + 262144);               // 256x256 bf16
  u16*  w3t = (u16*)(ws + 393216);               // 64x256 bf16
  float* lg = (float*)(ws + 458752);             // 65536x64 fp32

  (void)in_sizes; (void)n_in; (void)out_size; (void)ws_size;

  conv_weights<<<832, 256, 0, stream>>>(W1, W2, W3, w1t, w2t, w3t);
  mlp_kernel<<<1024, 256, 0, stream>>>(X, w1t, w2t, w3t, lg);
  topk_medoid<2><<<2048, 256, 0, stream>>>(ppr, lg, out);
}

// Round 10
// 264.290 us; speedup vs baseline: 1.9993x; 1.9993x over previous
//
#include <hip/hip_runtime.h>
#include <hip/hip_bf16.h>

typedef unsigned short u16;
typedef __attribute__((ext_vector_type(8))) __bf16 bf16x8;
typedef __attribute__((ext_vector_type(4))) float f32x4;

#define AS1 __attribute__((address_space(1)))
#define AS3 __attribute__((address_space(3)))

__device__ inline void gload_lds16(const void* g, void* l) {
  __builtin_amdgcn_global_load_lds((const AS1 void*)g, (AS3 void*)l, 16, 0, 0);
}

__device__ inline u16 f2bf(float f) {
  __bf16 h = (__bf16)f;
  return __builtin_bit_cast(u16, h);
}

// ---------------- fused weight transpose + bf16 convert ----------------
__global__ void conv_weights(const float* __restrict__ W1, const float* __restrict__ W2,
                             const float* __restrict__ W3, u16* __restrict__ w1t,
                             u16* __restrict__ w2t, u16* __restrict__ w3t) {
  int e = blockIdx.x * 256 + threadIdx.x;          // 0 .. 212991
  if (e < 131072) {
    int h = e >> 9, f = e & 511;
    w1t[e] = f2bf(W1[f * 256 + h]);
  } else if (e < 196608) {
    int x = e - 131072;
    int n = x >> 8, k = x & 255;
    w2t[x] = f2bf(W2[k * 256 + n]);
  } else if (e < 212992) {
    int x = e - 196608;
    int n = x >> 8, k = x & 255;
    w3t[x] = f2bf(W3[k * 64 + n]);
  }
}

// ================= scan kernel: pure streaming quarter-rows =================
// 8192 blocks: block (r,q)=(bid>>2, bid&3) scans ppr[r][q*16384 .. +16384).
// All 16 float4/thread issued before any consume (VGPR unconstrained: no
// min-waves launch_bounds -> compiler keeps them in flight, counted waits).
// Candidates (> T0=0.997, E~49/quarter, cap 256) -> cv/ci[bid][*]; exact count
// -> cq[bid]; fixed-order partial sum -> gs[bid]. No serial tail here.
__global__ __launch_bounds__(256) void scan_kernel(const float* __restrict__ ppr,
                                                   float* __restrict__ cv,
                                                   int* __restrict__ ci,
                                                   int* __restrict__ cq,
                                                   float* __restrict__ gs) {
  __shared__ int cnt;
  __shared__ float part[4];
  const int t = threadIdx.x, lane = t & 63, wid = t >> 6;
  const int q = blockIdx.x & 3;
  const float4* rp = (const float4*)(ppr + ((size_t)(blockIdx.x >> 2) * 65536 + q * 16384));
  const float T0 = 0.997f;
  if (t == 0) cnt = 0;
  __syncthreads();

  float4 v[16];
#pragma unroll
  for (int i = 0; i < 16; ++i) v[i] = rp[i * 256 + t];

  float sum = 0.f;
  float* cvb = cv + (size_t)blockIdx.x * 256;
  int*   cib = ci + (size_t)blockIdx.x * 256;
#pragma unroll
  for (int i = 0; i < 16; ++i) {
    float4 x = v[i];
    sum += (x.x + x.y) + (x.z + x.w);
    float mx = fmaxf(fmaxf(x.x, x.y), fmaxf(x.z, x.w));
    if (mx > T0) {
      float xs[4] = {x.x, x.y, x.z, x.w};
      int fb = q * 16384 + (i * 256 + t) * 4;
#pragma unroll
      for (int j = 0; j < 4; ++j) {
        if (xs[j] > T0) {
          int p = atomicAdd(&cnt, 1);
          if (p < 256) { cvb[p] = xs[j]; cib[p] = fb + j; }
        }
      }
    }
  }
#pragma unroll
  for (int off = 32; off > 0; off >>= 1) sum += __shfl_down(sum, off);
  if (lane == 0) part[wid] = sum;
  __syncthreads();
  if (t == 0) {
    gs[blockIdx.x] = (part[0] + part[1]) + (part[2] + part[3]);
    cq[blockIdx.x] = cnt;
  }
}

// ================= merge + extraction + medoid per row =================
// 2048 blocks. Load <=1024 candidates from the 4 quarter slices, wave0
// extracts top-32 ((val desc, idx asc) == jax.lax.top_k; order-independent of
// candidate storage order -> deterministic), rsum = fixed-order sum of the 4
// quarter sums, then the medoid. Fallback: exact global argmax if any quarter
// overflowed (>256) or total < 32 (never for uniform data).
__global__ __launch_bounds__(256) void merge_medoid(const float* __restrict__ ppr,
                                                    const float* __restrict__ cv,
                                                    const int* __restrict__ ci,
                                                    const int* __restrict__ cq,
                                                    const float* __restrict__ gs,
                                                    const float* __restrict__ lg,
                                                    float* __restrict__ out) {
  __shared__ alignas(16) char smem[13312];
  float* cvals = (float*)smem;              // [1024]
  int*   cidx  = (int*)(smem + 4096);       // [1024]
  float* xk    = (float*)smem;              // [32][65] (phase 3, aliases cands)
  float* l2m   = (float*)(smem + 8448);     // [32][33]
  float* vals  = (float*)(smem + 12672);    // [32]
  int*   idxs  = (int*)(smem + 12800);      // [32] (also fallback's sel)
  float* dist  = (float*)(smem + 12928);    // [32]
  float* wgt   = (float*)(smem + 13056);    // [32]
  float* rsum  = (float*)(smem + 13184);    // [1]

  const int b = blockIdx.x, t = threadIdx.x;
  const int lane = t & 63, wid = t >> 6;
  const float* row = ppr + (size_t)b * 65536;

  const int q0 = cq[b * 4 + 0], q1 = cq[b * 4 + 1], q2 = cq[b * 4 + 2], q3 = cq[b * 4 + 3];
  const int n0 = q0 < 256 ? q0 : 256, n1 = q1 < 256 ? q1 : 256,
            n2 = q2 < 256 ? q2 : 256, n3 = q3 < 256 ? q3 : 256;
  const int o1 = n0, o2 = n0 + n1, o3 = n0 + n1 + n2;
  const int n = o3 + n3;
  const bool ovf = (q0 > 256) | (q1 > 256) | (q2 > 256) | (q3 > 256);

  if (t < n0) { cvals[t]      = cv[(size_t)(b * 4 + 0) * 256 + t]; cidx[t]      = ci[(size_t)(b * 4 + 0) * 256 + t]; }
  if (t < n1) { cvals[o1 + t] = cv[(size_t)(b * 4 + 1) * 256 + t]; cidx[o1 + t] = ci[(size_t)(b * 4 + 1) * 256 + t]; }
  if (t < n2) { cvals[o2 + t] = cv[(size_t)(b * 4 + 2) * 256 + t]; cidx[o2 + t] = ci[(size_t)(b * 4 + 2) * 256 + t]; }
  if (t < n3) { cvals[o3 + t] = cv[(size_t)(b * 4 + 3) * 256 + t]; cidx[o3 + t] = ci[(size_t)(b * 4 + 3) * 256 + t]; }
  if (t == 0)
    *rsum = (gs[b * 4 + 0] + gs[b * 4 + 1]) + (gs[b * 4 + 2] + gs[b * 4 + 3]);
  __syncthreads();

  // ---- wave0 extraction ----
  if (wid == 0) {
    if (n >= 32 && !ovf) {
      for (int r = 0; r < 32; ++r) {
        float bv = -__builtin_inff();
        int bi = 0x7fffffff, bp = -1;
        for (int p = lane; p < n; p += 64) {
          float xv = cvals[p];
          int xi = cidx[p];
          if (xv > bv || (xv == bv && xi < bi)) { bv = xv; bi = xi; bp = p; }
        }
#pragma unroll
        for (int off = 32; off > 0; off >>= 1) {
          float ov = __shfl_down(bv, off);
          int   oi = __shfl_down(bi, off);
          int   op = __shfl_down(bp, off);
          if (ov > bv || (ov == bv && oi < bi)) { bv = ov; bi = oi; bp = op; }
        }
        if (lane == 0) {
          vals[r] = bv; idxs[r] = bi;
          if (bp >= 0) { cvals[bp] = -__builtin_inff(); cidx[bp] = 0x7fffffff; }
        }
      }
    } else {
      // exact fallback (never taken for uniform data)
      for (int r = 0; r < 32; ++r) {
        float bv = -__builtin_inff();
        int bi = 0x7fffffff;
        for (int p = lane; p < 65536; p += 64) {
          float xv = row[p];
          bool skip = false;
          for (int qq = 0; qq < r; ++qq) skip = skip || (idxs[qq] == p);
          if (!skip && (xv > bv || (xv == bv && p < bi))) { bv = xv; bi = p; }
        }
#pragma unroll
        for (int off = 32; off > 0; off >>= 1) {
          float ov = __shfl_down(bv, off);
          int   oi = __shfl_down(bi, off);
          if (ov > bv || (ov == bv && oi < bi)) { bv = ov; bi = oi; }
        }
        if (lane == 0) { vals[r] = bv; idxs[r] = bi; }
      }
    }
  }
  __syncthreads();

  // ---- medoid ----
  const float rs_b = *rsum;
#pragma unroll
  for (int j = 0; j < 8; ++j) {
    int s = j * 256 + t;
    int r = s >> 6, c = s & 63;
    xk[r * 65 + c] = lg[(size_t)idxs[r] * 64 + c];
  }
  __syncthreads();
#pragma unroll
  for (int j = 0; j < 4; ++j) {
    int p = j * 256 + t;
    int c = p >> 5, m = p & 31;
    float d = 0.f;
#pragma unroll
    for (int ch = 0; ch < 64; ++ch) {
      float df = xk[c * 65 + ch] - xk[m * 65 + ch];
      d += df * df;
    }
    l2m[c * 33 + m] = sqrtf(d + 1e-12f);
  }
  __syncthreads();
  if (t < 32) {
    float d = 0.f;
#pragma unroll
    for (int m = 0; m < 32; ++m) d += vals[m] * l2m[t * 33 + m];
    if (vals[t] == 0.f) d = 3.402823466e+38f;
    dist[t] = d;
  }
  __syncthreads();
  if (t == 0) {
    float mx = -3.402823466e+38f;
    for (int c = 0; c < 32; ++c) mx = fmaxf(mx, -dist[c]);
    float s = 0.f;
    for (int c = 0; c < 32; ++c) { float e = expf(-dist[c] - mx); wgt[c] = e; s += e; }
    float s2 = 0.f;
    for (int c = 0; c < 32; ++c) { wgt[c] = wgt[c] / s * vals[c]; s2 += wgt[c]; }
    float inv = 1.f / s2;
    for (int c = 0; c < 32; ++c) wgt[c] *= inv;
  }
  __syncthreads();
  if (t < 64) {
    float o = 0.f;
#pragma unroll
    for (int k = 0; k < 32; ++k) o += wgt[k] * xk[k * 65 + t];
    out[(size_t)b * 64 + t] = rs_b * o;
  }
}

// ================= fully-fused MLP (unchanged from R8) =================
__global__ __launch_bounds__(256, 2) void mlp_kernel(const float* __restrict__ X,
                                                     const u16* __restrict__ W1t,
                                                     const u16* __restrict__ W2t,
                                                     const u16* __restrict__ W3t,
                                                     float* __restrict__ lg) {
  __shared__ alignas(16) char smem[69632];
  u16* As   = (u16*)smem;                 // [64][32]   4 KB
  u16* Bs   = (u16*)(smem + 4096);        // [256][32] 16 KB
  u16* h1s  = (u16*)(smem + 20480);       // [64][256] 32 KB, elem-idx ^ ((row&7)<<3)
  u16* quad = (u16*)(smem + 53248);       // [64][64]   8 KB, swizzled
  u16* w3s  = (u16*)(smem + 61440);       // [64][64]   8 KB, swizzled
  const int bm = blockIdx.x, t = threadIdx.x;
  const int wid = t >> 6, lane = t & 63;
  const int wr = wid >> 1, wc = wid & 1;
  const int l15 = lane & 15, lk = lane >> 4;
  const f32x4 z = {0.f, 0.f, 0.f, 0.f};

  // ---- phase 1: h1s = relu(X[bm stripe] @ W1) ----
  {
    f32x4 acc[2][8];
#pragma unroll
    for (int i = 0; i < 2; ++i)
#pragma unroll
      for (int j = 0; j < 8; ++j) acc[i][j] = z;

    for (int k0 = 0; k0 < 512; k0 += 32) {
#pragma unroll
      for (int it = 0; it < 4; ++it) {
        int s = it * 256 + t;
        gload_lds16(W1t + (size_t)(s >> 2) * 512 + k0 + (s & 3) * 8,
                    &Bs[(it * 256 + wid * 64) * 8]);
      }
      {
        const float* src = X + (size_t)(bm * 64 + (t >> 2)) * 512 + k0 + (t & 3) * 8;
        float4 v0 = *(const float4*)src;
        float4 v1 = *(const float4*)(src + 4);
        bf16x8 wv;
        wv[0] = (__bf16)v0.x; wv[1] = (__bf16)v0.y; wv[2] = (__bf16)v0.z; wv[3] = (__bf16)v0.w;
        wv[4] = (__bf16)v1.x; wv[5] = (__bf16)v1.y; wv[6] = (__bf16)v1.z; wv[7] = (__bf16)v1.w;
        *(bf16x8*)&As[t * 8] = wv;
      }
      __syncthreads();
      bf16x8 af[2], bfr[8];
#pragma unroll
      for (int i = 0; i < 2; ++i)
        af[i] = *(const bf16x8*)&As[(wr * 32 + i * 16 + l15) * 32 + lk * 8];
#pragma unroll
      for (int j = 0; j < 8; ++j)
        bfr[j] = *(const bf16x8*)&Bs[(wc * 128 + j * 16 + l15) * 32 + lk * 8];
#pragma unroll
      for (int i = 0; i < 2; ++i)
#pragma unroll
        for (int j = 0; j < 8; ++j)
          acc[i][j] = __builtin_amdgcn_mfma_f32_16x16x32_bf16(af[i], bfr[j], acc[i][j], 0, 0, 0);
      __syncthreads();
    }
#pragma unroll
    for (int i = 0; i < 2; ++i)
#pragma unroll
      for (int j = 0; j < 8; ++j)
#pragma unroll
        for (int r = 0; r < 4; ++r) {
          int row = wr * 32 + i * 16 + lk * 4 + r;
          int col = wc * 128 + j * 16 + l15;
          h1s[(row * 256 + col) ^ ((row & 7) << 3)] = f2bf(fmaxf(acc[i][j][r], 0.f));
        }
    __syncthreads();
  }

  // ---- phase 2: acc2 = h1s @ W2 ----
  f32x4 acc2[2][8];
#pragma unroll
  for (int i = 0; i < 2; ++i)
#pragma unroll
    for (int j = 0; j < 8; ++j) acc2[i][j] = z;

  for (int k0 = 0; k0 < 256; k0 += 32) {
#pragma unroll
    for (int it = 0; it < 4; ++it) {
      int s = it * 256 + t;
      gload_lds16(W2t + (size_t)(s >> 2) * 256 + k0 + (s & 3) * 8,
                  &Bs[(it * 256 + wid * 64) * 8]);
    }
    __syncthreads();
    bf16x8 af[2], bfr[8];
#pragma unroll
    for (int i = 0; i < 2; ++i) {
      int row = wr * 32 + i * 16 + l15;
      af[i] = *(const bf16x8*)&h1s[(row * 256 + k0 + lk * 8) ^ ((row & 7) << 3)];
    }
#pragma unroll
    for (int j = 0; j < 8; ++j)
      bfr[j] = *(const bf16x8*)&Bs[(wc * 128 + j * 16 + l15) * 32 + lk * 8];
#pragma unroll
    for (int i = 0; i < 2; ++i)
#pragma unroll
      for (int j = 0; j < 8; ++j)
        acc2[i][j] = __builtin_amdgcn_mfma_f32_16x16x32_bf16(af[i], bfr[j], acc2[i][j], 0, 0, 0);
    __syncthreads();
  }

  // ---- phase 3: lg = relu(acc2) @ W3 via swizzled LDS bounce ----
  f32x4 acc3[4];
#pragma unroll
  for (int j = 0; j < 4; ++j) acc3[j] = z;

#pragma unroll
  for (int kk = 0; kk < 4; ++kk) {
    if (wc == (kk >> 1)) {
#pragma unroll
      for (int i = 0; i < 2; ++i)
#pragma unroll
        for (int j4 = 0; j4 < 4; ++j4) {
          int j = (kk & 1) * 4 + j4;
#pragma unroll
          for (int r = 0; r < 4; ++r) {
            int row = wr * 32 + i * 16 + lk * 4 + r;
            int c   = j4 * 16 + l15;
            quad[(row * 64 + c) ^ ((row & 7) << 3)] = f2bf(fmaxf(acc2[i][j][r], 0.f));
          }
        }
    }
#pragma unroll
    for (int it = 0; it < 2; ++it) {
      int s = it * 256 + t;
      int col = s >> 3;
      int koff = ((s ^ (col & 7)) & 7) * 8;
      gload_lds16(W3t + (size_t)col * 256 + kk * 64 + koff, &w3s[(it * 256 + wid * 64) * 8]);
    }
    __syncthreads();
    bf16x8 af2, bfr2[4];
#pragma unroll
    for (int ks = 0; ks < 2; ++ks) {
#pragma unroll
      for (int j2 = 0; j2 < 4; ++j2) {
        int col = j2 * 16 + l15;
        bfr2[j2] = *(const bf16x8*)&w3s[(col * 64 + ks * 32 + lk * 8) ^ ((col & 7) << 3)];
      }
      {
        int row = wid * 16 + l15;
        af2 = *(const bf16x8*)&quad[(row * 64 + ks * 32 + lk * 8) ^ ((row & 7) << 3)];
      }
#pragma unroll
      for (int j2 = 0; j2 < 4; ++j2)
        acc3[j2] = __builtin_amdgcn_mfma_f32_16x16x32_bf16(af2, bfr2[j2], acc3[j2], 0, 0, 0);
    }
    __syncthreads();
  }

#pragma unroll
  for (int j2 = 0; j2 < 4; ++j2) {
    int col = j2 * 16 + l15;
#pragma unroll
    for (int r = 0; r < 4; ++r) {
      int row = wid * 16 + lk * 4 + r;
      lg[(size_t)(bm * 64 + row) * 64 + col] = acc3[j2][r];
    }
  }
}

// ---------------- launch ----------------
extern "C" void kernel_launch(void* const* d_in, const int* in_sizes, int n_in,
                              void* d_out, int out_size, void* d_ws, size_t ws_size,
                              hipStream_t stream) {
  const float* X   = (const float*)d_in[0];
  const float* ppr = (const float*)d_in[1];
  const float* W1  = (const float*)d_in[2];
  const float* W2  = (const float*)d_in[3];
  const float* W3  = (const float*)d_in[4];
  float* out = (float*)d_out;
  char* ws = (char*)d_ws;

  u16*  w1t = (u16*)(ws + 0);                    // 256x512 bf16
  u16*  w2t = (u16*)(ws + 262144);               // 256x256 bf16
  u16*  w3t = (u16*)(ws + 393216);               // 64x256 bf16
  float* lg = (float*)(ws + 458752);             // 65536x64 fp32 (16 MB)
  float* cv = (float*)(ws + 17235968);           // 8192x256 cand vals (8 MB)
  int*   ci = (int*)(ws + 25624576);             // 8192x256 cand idx (8 MB)
  int*   cq = (int*)(ws + 34013184);             // 8192 counts
  float* gs = (float*)(ws + 34045952);           // 8192 partial sums

  (void)in_sizes; (void)n_in; (void)out_size; (void)ws_size;

  conv_weights<<<832, 256, 0, stream>>>(W1, W2, W3, w1t, w2t, w3t);
  scan_kernel<<<8192, 256, 0, stream>>>(ppr, cv, ci, cq, gs);
  mlp_kernel<<<1024, 256, 0, stream>>>(X, w1t, w2t, w3t, lg);
  merge_medoid<<<2048, 256, 0, stream>>>(ppr, cv, ci, cq, gs, lg, out);
}